// Round 1
// baseline (3678.646 us; speedup 1.0000x reference)
//
#include <hip/hip_runtime.h>
#include <math.h>

// CGConv: N=100000 atoms, M=12 nbrs, F=64 atom-feat, B=41 bond-feat
// gated = [self | nbr | bond] @ W + b ; BN1 over N*M rows ;
// summed = sum_j sigmoid(filter)*softplus(core) ; BN2 over N rows ;
// out = softplus(atom + summed_bn)
//
// Decomposition: W rows split into W_self(64x128), W_nbr(64x128), W_bond(41x128).
// Pself = atom@W_self, Pnbr = atom@W_nbr precomputed per-atom (kernel 1).
// Per-pair work is then only the K=41 bond dot (kernels 2 & 4, recomputed
// twice because BN1 batch stats must be known before the nonlinearity).

#define NATOMS  100000
#define MNBR    12
#define FDIM    64
#define BDIM    41
#define C2F     128
#define BONDROW (MNBR*BDIM)   // 492
#define EPSBN   1e-5f
#define NB1     1024          // grid for pair kernels (also #partial slots)

__device__ __forceinline__ float softplusf(float x) {
    return fmaxf(x, 0.f) + log1pf(__expf(-fabsf(x)));
}
__device__ __forceinline__ float sigmoidf(float x) {
    return 1.f / (1.f + __expf(-x));
}

// ---------------- kernel 1: per-atom projections ----------------
// Pself[i][c] = sum_k atom[i][k] * W[k][c]
// Pnbr [i][c] = sum_k atom[i][k] * W[64+k][c]
__global__ __launch_bounds__(256) void k_project(
    const float* __restrict__ atom, const float* __restrict__ W,
    float* __restrict__ Pself, float* __restrict__ Pnbr)
{
    __shared__ float Arow[8][64];
    const int tid  = threadIdx.x;
    const int c    = tid & 127;
    const int half = tid >> 7;           // 0 -> Pself, 1 -> Pnbr
    float w[64];
    #pragma unroll
    for (int k = 0; k < 64; ++k)
        w[k] = W[(half*64 + k)*C2F + c]; // W column c, register-cached
    float* Pout = half ? Pnbr : Pself;

    for (int i0 = blockIdx.x*8; i0 < NATOMS; i0 += gridDim.x*8) {
        __syncthreads();
        for (int idx = tid; idx < 8*64; idx += 256) {
            int a = idx >> 6, k = idx & 63, i = i0 + a;
            Arow[a][k] = (i < NATOMS) ? atom[i*FDIM + k] : 0.f;
        }
        __syncthreads();
        #pragma unroll
        for (int a = 0; a < 8; ++a) {
            int i = i0 + a;
            if (i >= NATOMS) break;
            const float4* A4 = (const float4*)Arow[a];
            float s = 0.f;
            #pragma unroll
            for (int kk = 0; kk < 16; ++kk) {
                float4 v = A4[kk];
                s += v.x*w[4*kk] + v.y*w[4*kk+1] + v.z*w[4*kk+2] + v.w*w[4*kk+3];
            }
            Pout[i*C2F + c] = s;
        }
    }
}

// ---------------- kernel 2: BN1 batch statistics ----------------
// Recompute gated per pair, accumulate per-channel sum & sumsq.
// 256 threads = 4 atom slots x 64 channels; thread owns channels f and f+64.
__global__ __launch_bounds__(256) void k_bn1_stats(
    const int*   __restrict__ nbr,  const float* __restrict__ bond,
    const float* __restrict__ W,    const float* __restrict__ bvec,
    const float* __restrict__ Pself,const float* __restrict__ Pnbr,
    float* __restrict__ partial1)
{
    __shared__ float BondL[4][MNBR][44]; // padded to 44 for aligned float4 reads
    __shared__ int   Ni[4][MNBR];
    __shared__ float red[256];
    const int tid  = threadIdx.x;
    const int f    = tid & 63;
    const int slot = tid >> 6;
    float wf[BDIM], wc[BDIM];
    #pragma unroll
    for (int k = 0; k < BDIM; ++k) {
        wf[k] = W[(C2F + k)*C2F + f];
        wc[k] = W[(C2F + k)*C2F + f + 64];
    }
    const float bb0 = bvec[f], bb1 = bvec[f + 64];
    float s0 = 0.f, q0 = 0.f, s1 = 0.f, q1 = 0.f;

    for (int i0 = blockIdx.x*4; i0 < NATOMS; i0 += gridDim.x*4) {
        __syncthreads();
        for (int idx = tid; idx < 4*BONDROW; idx += 256) {
            int a = idx / BONDROW, r = idx - a*BONDROW;
            int i = i0 + a;
            if (i < NATOMS) BondL[a][r/BDIM][r%BDIM] = bond[i*BONDROW + r];
        }
        if (tid < 4*MNBR) {
            int a = tid / MNBR, j = tid - a*MNBR, i = i0 + a;
            if (i < NATOMS) Ni[a][j] = nbr[i*MNBR + j];
        }
        __syncthreads();
        const int i = i0 + slot;
        if (i < NATOMS) {
            const float pf0 = Pself[i*C2F + f];
            const float pf1 = Pself[i*C2F + f + 64];
            #pragma unroll
            for (int j = 0; j < MNBR; ++j) {
                const int r = Ni[slot][j];
                float g0 = pf0 + bb0 + Pnbr[r*C2F + f];
                float g1 = pf1 + bb1 + Pnbr[r*C2F + f + 64];
                const float* brow = BondL[slot][j];
                #pragma unroll
                for (int kk = 0; kk < 10; ++kk) {
                    float4 v = *(const float4*)(brow + 4*kk);
                    g0 += v.x*wf[4*kk] + v.y*wf[4*kk+1] + v.z*wf[4*kk+2] + v.w*wf[4*kk+3];
                    g1 += v.x*wc[4*kk] + v.y*wc[4*kk+1] + v.z*wc[4*kk+2] + v.w*wc[4*kk+3];
                }
                const float bl = brow[40];
                g0 += bl*wf[40]; g1 += bl*wc[40];
                s0 += g0; q0 += g0*g0; s1 += g1; q1 += g1*g1;
            }
        }
    }
    // deterministic block reduction -> partial1[blk][256] = {sum[128], sumsq[128]}
    float* pb = partial1 + blockIdx.x*256;
    red[tid] = s0; __syncthreads();
    if (tid < 64) pb[tid]       = red[tid] + red[tid+64] + red[tid+128] + red[tid+192];
    __syncthreads();
    red[tid] = s1; __syncthreads();
    if (tid < 64) pb[64 + tid]  = red[tid] + red[tid+64] + red[tid+128] + red[tid+192];
    __syncthreads();
    red[tid] = q0; __syncthreads();
    if (tid < 64) pb[128 + tid] = red[tid] + red[tid+64] + red[tid+128] + red[tid+192];
    __syncthreads();
    red[tid] = q1; __syncthreads();
    if (tid < 64) pb[192 + tid] = red[tid] + red[tid+64] + red[tid+128] + red[tid+192];
}

// ---------------- kernel 3: finalize BN1 params ----------------
__global__ __launch_bounds__(256) void k_bn1_finalize(
    const float* __restrict__ partial1, const float* __restrict__ scale,
    const float* __restrict__ offset,   float* __restrict__ prm1)
{
    __shared__ float red[512];
    const int tid = threadIdx.x;
    const int c = tid & 127, h = tid >> 7;
    float S = 0.f, Q = 0.f;
    for (int blk = h; blk < NB1; blk += 2) {
        S += partial1[blk*256 + c];
        Q += partial1[blk*256 + 128 + c];
    }
    red[tid] = S; red[256 + tid] = Q;
    __syncthreads();
    if (tid < 128) {
        float Sa = red[c] + red[128 + c];
        float Qa = red[256 + c] + red[384 + c];
        const float invn = 1.f / (float)(NATOMS * MNBR);
        float mean = Sa * invn;
        float var  = Qa * invn - mean*mean;
        float inv  = scale[c] * rsqrtf(var + EPSBN);
        prm1[c]       = inv;
        prm1[128 + c] = offset[c] - mean*inv;  // folded offset
    }
}

// ---------------- kernel 4: main pass ----------------
// Recompute gated, apply BN1, gate = sigmoid(filter)*softplus(core),
// sum over neighbors -> summed[i][f]; accumulate BN2 stats.
__global__ __launch_bounds__(256) void k_main(
    const int*   __restrict__ nbr,  const float* __restrict__ bond,
    const float* __restrict__ W,    const float* __restrict__ bvec,
    const float* __restrict__ Pself,const float* __restrict__ Pnbr,
    const float* __restrict__ prm1,
    float* __restrict__ summed, float* __restrict__ partial2)
{
    __shared__ float BondL[4][MNBR][44];
    __shared__ int   Ni[4][MNBR];
    __shared__ float red[256];
    const int tid  = threadIdx.x;
    const int f    = tid & 63;
    const int slot = tid >> 6;
    float wf[BDIM], wc[BDIM];
    #pragma unroll
    for (int k = 0; k < BDIM; ++k) {
        wf[k] = W[(C2F + k)*C2F + f];
        wc[k] = W[(C2F + k)*C2F + f + 64];
    }
    const float bb0 = bvec[f], bb1 = bvec[f + 64];
    const float iv0 = prm1[f],      of0 = prm1[128 + f];
    const float iv1 = prm1[f + 64], of1 = prm1[192 + f];
    float s2 = 0.f, q2 = 0.f;

    for (int i0 = blockIdx.x*4; i0 < NATOMS; i0 += gridDim.x*4) {
        __syncthreads();
        for (int idx = tid; idx < 4*BONDROW; idx += 256) {
            int a = idx / BONDROW, r = idx - a*BONDROW;
            int i = i0 + a;
            if (i < NATOMS) BondL[a][r/BDIM][r%BDIM] = bond[i*BONDROW + r];
        }
        if (tid < 4*MNBR) {
            int a = tid / MNBR, j = tid - a*MNBR, i = i0 + a;
            if (i < NATOMS) Ni[a][j] = nbr[i*MNBR + j];
        }
        __syncthreads();
        const int i = i0 + slot;
        if (i < NATOMS) {
            const float pf0 = Pself[i*C2F + f];
            const float pf1 = Pself[i*C2F + f + 64];
            float acc = 0.f;
            #pragma unroll
            for (int j = 0; j < MNBR; ++j) {
                const int r = Ni[slot][j];
                float g0 = pf0 + bb0 + Pnbr[r*C2F + f];
                float g1 = pf1 + bb1 + Pnbr[r*C2F + f + 64];
                const float* brow = BondL[slot][j];
                #pragma unroll
                for (int kk = 0; kk < 10; ++kk) {
                    float4 v = *(const float4*)(brow + 4*kk);
                    g0 += v.x*wf[4*kk] + v.y*wf[4*kk+1] + v.z*wf[4*kk+2] + v.w*wf[4*kk+3];
                    g1 += v.x*wc[4*kk] + v.y*wc[4*kk+1] + v.z*wc[4*kk+2] + v.w*wc[4*kk+3];
                }
                const float bl = brow[40];
                g0 += bl*wf[40]; g1 += bl*wc[40];
                float y0 = g0*iv0 + of0;   // BN1 filter channel
                float y1 = g1*iv1 + of1;   // BN1 core channel
                acc += sigmoidf(y0) * softplusf(y1);
            }
            summed[i*FDIM + f] = acc;
            s2 += acc; q2 += acc*acc;
        }
    }
    float* pb = partial2 + blockIdx.x*128;
    red[tid] = s2; __syncthreads();
    if (tid < 64) pb[tid]      = red[tid] + red[tid+64] + red[tid+128] + red[tid+192];
    __syncthreads();
    red[tid] = q2; __syncthreads();
    if (tid < 64) pb[64 + tid] = red[tid] + red[tid+64] + red[tid+128] + red[tid+192];
}

// ---------------- kernel 5: finalize BN2 params ----------------
__global__ __launch_bounds__(256) void k_bn2_finalize(
    const float* __restrict__ partial2, const float* __restrict__ scale,
    const float* __restrict__ offset,   float* __restrict__ prm2)
{
    __shared__ float red[512];
    const int tid = threadIdx.x;
    const int f = tid & 63, h = tid >> 6;
    float S = 0.f, Q = 0.f;
    for (int blk = h; blk < NB1; blk += 4) {
        S += partial2[blk*128 + f];
        Q += partial2[blk*128 + 64 + f];
    }
    red[tid] = S; red[256 + tid] = Q;
    __syncthreads();
    if (tid < 64) {
        float Sa = red[f] + red[64+f] + red[128+f] + red[192+f];
        float Qa = red[256+f] + red[320+f] + red[384+f] + red[448+f];
        const float invn = 1.f / (float)NATOMS;
        float mean = Sa * invn;
        float var  = Qa * invn - mean*mean;
        float inv  = scale[f] * rsqrtf(var + EPSBN);
        prm2[f]      = inv;
        prm2[64 + f] = offset[f] - mean*inv;
    }
}

// ---------------- kernel 6: residual + softplus ----------------
__global__ __launch_bounds__(256) void k_final(
    const float* __restrict__ atom, const float* __restrict__ summed,
    const float* __restrict__ prm2, float* __restrict__ out)
{
    __shared__ float iv[64], of[64];
    if (threadIdx.x < 64) {
        iv[threadIdx.x] = prm2[threadIdx.x];
        of[threadIdx.x] = prm2[64 + threadIdx.x];
    }
    __syncthreads();
    const int total4 = NATOMS*FDIM/4;
    for (int t = blockIdx.x*blockDim.x + threadIdx.x; t < total4;
         t += gridDim.x*blockDim.x) {
        float4 a = ((const float4*)atom)[t];
        float4 s = ((const float4*)summed)[t];
        int fb = (t*4) & 63;
        float4 r;
        r.x = softplusf(a.x + s.x*iv[fb]   + of[fb]);
        r.y = softplusf(a.y + s.y*iv[fb+1] + of[fb+1]);
        r.z = softplusf(a.z + s.z*iv[fb+2] + of[fb+2]);
        r.w = softplusf(a.w + s.w*iv[fb+3] + of[fb+3]);
        ((float4*)out)[t] = r;
    }
}

extern "C" void kernel_launch(void* const* d_in, const int* in_sizes, int n_in,
                              void* d_out, int out_size, void* d_ws, size_t ws_size,
                              hipStream_t stream)
{
    const int*   nbr  = (const int*)  d_in[0];
    const float* atom = (const float*)d_in[1];
    const float* bond = (const float*)d_in[2];
    const float* W    = (const float*)d_in[3];
    const float* bvec = (const float*)d_in[4];
    const float* s1   = (const float*)d_in[5];
    const float* o1   = (const float*)d_in[6];
    const float* s2   = (const float*)d_in[7];
    const float* o2   = (const float*)d_in[8];
    float* out = (float*)d_out;

    float* ws       = (float*)d_ws;
    float* Pself    = ws;                                  // N*128
    float* Pnbr     = Pself    + (size_t)NATOMS*C2F;       // N*128
    float* summed   = Pnbr     + (size_t)NATOMS*C2F;       // N*64
    float* partial1 = summed   + (size_t)NATOMS*FDIM;      // NB1*256
    float* partial2 = partial1 + (size_t)NB1*256;          // NB1*128
    float* prm1     = partial2 + (size_t)NB1*128;          // 256
    float* prm2     = prm1     + 256;                      // 128

    hipLaunchKernelGGL(k_project,      dim3(512),  dim3(256), 0, stream,
                       atom, W, Pself, Pnbr);
    hipLaunchKernelGGL(k_bn1_stats,    dim3(NB1),  dim3(256), 0, stream,
                       nbr, bond, W, bvec, Pself, Pnbr, partial1);
    hipLaunchKernelGGL(k_bn1_finalize, dim3(1),    dim3(256), 0, stream,
                       partial1, s1, o1, prm1);
    hipLaunchKernelGGL(k_main,         dim3(NB1),  dim3(256), 0, stream,
                       nbr, bond, W, bvec, Pself, Pnbr, prm1, summed, partial2);
    hipLaunchKernelGGL(k_bn2_finalize, dim3(1),    dim3(256), 0, stream,
                       partial2, s2, o2, prm2);
    hipLaunchKernelGGL(k_final,        dim3(2048), dim3(256), 0, stream,
                       atom, summed, prm2, out);
}